// Round 4
// baseline (298.704 us; speedup 1.0000x reference)
//
#include <hip/hip_runtime.h>
#include <hip/hip_fp16.h>
#include <hip/hip_bf16.h>
#include <stdint.h>

#define TILE 128
#define BK 32
#define LDST 40   // B-tile pad: 80B row stride keeps 16B alignment, <=2-way bank alias

typedef __attribute__((ext_vector_type(8))) short short8;
typedef __attribute__((ext_vector_type(8))) unsigned short ushort8;
typedef __attribute__((ext_vector_type(4))) float f32x4;

typedef const __attribute__((address_space(1))) void* gptr_t;
typedef __attribute__((address_space(3))) void* lptr_t;

static __device__ __forceinline__ unsigned short f2bf(float f) {
    union { float f; uint32_t u; } v; v.f = f;
    uint32_t u = v.u;
    u += 0x7fffu + ((u >> 16) & 1u);   // RNE
    return (unsigned short)(u >> 16);
}

static __device__ __forceinline__ unsigned int pk_bf16(float a, float b) {
    __hip_bfloat162 h = __float22bfloat162_rn(float2{a, b});   // v_cvt_pk_bf16_f32 (RNE)
    union { __hip_bfloat162 h; unsigned int u; } c; c.h = h;
    return c.u;
}

// xp tiled layout: [b][r>>6][t>>4][r&63][t&15] fp16
// idx = ((((b*8 + (r>>6))*64 + (t>>4))*64 + (r&63))*16 + (t&15)

// ---------------- W transpose+convert: Wt[n][k] bf16 from W[k][n] fp32 ----------------
__global__ __launch_bounds__(256)
void wt_kernel(const float* __restrict__ W, unsigned short* __restrict__ Wt)
{
    __shared__ float s[32][33];
    const int tx = threadIdx.x;          // 0..31
    const int ty = threadIdx.y;          // 0..7
    const int kBase = blockIdx.x * 32;
    const int nBase = blockIdx.y * 32;
    #pragma unroll
    for (int j = 0; j < 4; ++j)
        s[ty + 8 * j][tx] = W[(size_t)(kBase + ty + 8 * j) * 512 + nBase + tx];
    __syncthreads();
    #pragma unroll
    for (int j = 0; j < 4; ++j)
        Wt[(size_t)(nBase + ty + 8 * j) * 512 + kBase + tx] = f2bf(s[tx][ty + 8 * j]);
}

// ---------------- xp = x @ W + b  (M=65536, K=512, N=512) ----------------
// A: fp32 X staged raw into LDS via global_load_lds (16B), source pre-swizzled
//    chunk j -> j^(m&7) so frag-side reads are ~conflict-free; cvt to bf16 in regs.
// B: bf16 Wt[n][k], reg-staged into padded LDS (L2-resident, cheap).
// F16OUT: MFMA operands swapped -> C^T fragment (lane axis = t) -> coalesced tiled stores.
template <bool F16OUT>
__global__ __launch_bounds__(256, 2)
void gemm_bias_kernel(const float* __restrict__ X, const unsigned short* __restrict__ Wt,
                      const float* __restrict__ bias,
                      float* __restrict__ out32, __half* __restrict__ xpT)
{
    __shared__ float Asf[TILE * 32];               // 16 KB, linear (gload_lds dest)
    __shared__ unsigned short Bs[TILE * LDST];     // 10 KB, padded

    const int tid = threadIdx.x;

    // XCD-chunked tile remap: lin%8 -> XCD; each XCD gets 64 consecutive m-tiles
    // x 4 n-tiles so blocks sharing an X stripe share an L2.
    const int lin = blockIdx.x;          // 0..2047
    const int xcd = lin & 7;
    const int idx = lin >> 3;            // 0..255
    const int rowBase = (xcd * 64 + (idx >> 2)) * TILE;
    const int colBase = (idx & 3) * TILE;

    const int wave  = tid >> 6;
    const int lane  = tid & 63;
    const int m16   = lane & 15;
    const int quad  = lane >> 4;
    const int waveM = wave & 1;
    const int waveN = wave >> 1;

    f32x4 acc[4][4] = {};

    const int srow = tid >> 2;   // 0..63 (B staging)
    const int sc4  = tid & 3;    // 0..3

    for (int kt = 0; kt < 512; kt += BK) {
        // ---- stage A: 128x32 fp32 via global_load_lds dwordx4, swizzled source ----
        #pragma unroll
        for (int i = 0; i < 4; ++i) {
            const int cbase = i * 256 + wave * 64;        // wave-uniform chunk base
            const int c = cbase + lane;                   // 16B chunk index 0..1023
            const int m = c >> 3, j = c & 7;
            const float* src = X + (size_t)(rowBase + m) * 512 + kt + ((j ^ (m & 7)) * 4);
            __builtin_amdgcn_global_load_lds((gptr_t)src,
                                             (lptr_t)((char*)Asf + cbase * 16),
                                             16, 0, 0);
        }
        // ---- stage B: 128 x 32 bf16, straight copy from Wt, ushort8 ----
        #pragma unroll
        for (int p = 0; p < 2; ++p) {
            int n = p * 64 + srow;
            ushort8 v = *(const ushort8*)(Wt + (size_t)(colBase + n) * 512 + kt + sc4 * 8);
            *(ushort8*)(&Bs[n * LDST + sc4 * 8]) = v;
        }
        __syncthreads();

        short8 a_frag[4], b_frag[4];
        #pragma unroll
        for (int mi = 0; mi < 4; ++mi) {
            int r = waveM * 64 + mi * 16 + m16;
            const float* rowp = Asf + r * 32;
            int g0 = (quad * 2)     ^ (r & 7);
            int g1 = (quad * 2 + 1) ^ (r & 7);
            float4 fa0 = *(const float4*)(rowp + g0 * 4);
            float4 fa1 = *(const float4*)(rowp + g1 * 4);
            union { short8 s8; unsigned int u[4]; } af;
            af.u[0] = pk_bf16(fa0.x, fa0.y); af.u[1] = pk_bf16(fa0.z, fa0.w);
            af.u[2] = pk_bf16(fa1.x, fa1.y); af.u[3] = pk_bf16(fa1.z, fa1.w);
            a_frag[mi] = af.s8;
        }
        #pragma unroll
        for (int ni = 0; ni < 4; ++ni)
            b_frag[ni] = *(const short8*)&Bs[(waveN * 64 + ni * 16 + m16) * LDST + quad * 8];

        #pragma unroll
        for (int mi = 0; mi < 4; ++mi)
            #pragma unroll
            for (int ni = 0; ni < 4; ++ni) {
                if (F16OUT)   // swapped -> acc holds C^T fragment (lane axis = t)
                    acc[mi][ni] = __builtin_amdgcn_mfma_f32_16x16x32_bf16(
                        b_frag[ni], a_frag[mi], acc[mi][ni], 0, 0, 0);
                else
                    acc[mi][ni] = __builtin_amdgcn_mfma_f32_16x16x32_bf16(
                        a_frag[mi], b_frag[ni], acc[mi][ni], 0, 0, 0);
            }
        __syncthreads();
    }

    if (F16OUT) {
        // transposed frag: lane axis (m16) = t (te = m16 exactly), reg axis = r
        const int bb = rowBase >> 10;          // whole 128-row tile sits in one b
        #pragma unroll
        for (int ni = 0; ni < 4; ++ni) {
            int r0 = colBase + waveN * 64 + ni * 16 + quad * 4;
            float4 b4 = *(const float4*)&bias[r0];
            #pragma unroll
            for (int mi = 0; mi < 4; ++mi) {
                int tc = ((rowBase + waveM * 64 + mi * 16) & 1023) >> 4;
                #pragma unroll
                for (int rr = 0; rr < 4; ++rr) {
                    int r = r0 + rr;
                    size_t off = ((((size_t)bb * 8 + (r >> 6)) * 64 + tc) * 64 + (r & 63)) * 16 + m16;
                    xpT[off] = __float2half_rn(acc[mi][ni][rr] + ((const float*)&b4)[rr]);
                }
            }
        }
    } else {
        // standard layout: col=lane&15, row=quad*4+reg
        #pragma unroll
        for (int ni = 0; ni < 4; ++ni) {
            int col = colBase + waveN * 64 + ni * 16 + m16;
            float bv = bias[col];
            #pragma unroll
            for (int mi = 0; mi < 4; ++mi) {
                int row0 = rowBase + waveM * 64 + mi * 16 + quad * 4;
                #pragma unroll
                for (int r = 0; r < 4; ++r) {
                    float v = acc[mi][ni][r] + bv;
                    out32[(size_t)(row0 + r) * 512 + col] = v;
                }
            }
        }
    }
}

// ---------------- scan: h_t = relu(xp_t + u*h_{t-1}), h_0 = 1 ----------------
// tiled xp: wave loads are contiguous (lane stride 16B) -> few line transactions,
// 16-deep prefetch = 16KB/wave in flight.
#define SUNR 128

__global__ __launch_bounds__(64)
void scan_t_kernel(const __half* __restrict__ xpT, float* __restrict__ out,
                   const float* __restrict__ u)
{
    const int l  = threadIdx.x;               // 0..63 = r&63
    const int b  = blockIdx.x >> 3;
    const int rg = blockIdx.x & 7;
    const int r  = rg * 64 + l;
    const float ur = u[r];
    const unsigned short* pt = (const unsigned short*)xpT
        + ((size_t)(b * 8 + rg) * 64) * 1024 + l * 16;   // + tc*1024
    float* po = out + (size_t)b * 1024 * 512 + r;

    float h = 1.0f;
    ushort8 cur[16], nxt[16];
    #pragma unroll
    for (int j = 0; j < 16; ++j)
        cur[j] = *(const ushort8*)(pt + (j >> 1) * 1024 + (j & 1) * 8);

    for (int t0 = 0; t0 < 1024; t0 += SUNR) {
        const bool more = (t0 + SUNR) < 1024;
        if (more) {
            const unsigned short* pn = pt + (size_t)((t0 + SUNR) >> 4) * 1024;
            #pragma unroll
            for (int j = 0; j < 16; ++j)
                nxt[j] = *(const ushort8*)(pn + (j >> 1) * 1024 + (j & 1) * 8);
        }
        #pragma unroll
        for (int j = 0; j < 16; ++j) {
            #pragma unroll
            for (int e = 0; e < 8; ++e) {
                float xv = __half2float(__ushort_as_half(cur[j][e]));
                h = fmaxf(fmaf(ur, h, xv), 0.0f);
                __builtin_nontemporal_store(h, po + (size_t)(t0 + j * 8 + e) * 512);
            }
        }
        #pragma unroll
        for (int j = 0; j < 16; ++j) cur[j] = nxt[j];
    }
}

// fp32 in-place fallback (xp in out, [B,T,R] layout)
#define UNR 32
__global__ __launch_bounds__(64)
void scan_f32_kernel(float* __restrict__ out, const float* __restrict__ u)
{
    const int gid = blockIdx.x * 64 + threadIdx.x;
    const int b = gid >> 9;
    const int r = gid & 511;
    const float ur = u[r];
    float* p = out + (size_t)b * 1024 * 512 + r;

    float h = 1.0f;
    float cur[UNR], nxt[UNR];
    #pragma unroll
    for (int j = 0; j < UNR; ++j) cur[j] = p[(size_t)j * 512];

    for (int t0 = 0; t0 < 1024; t0 += UNR) {
        const bool more = (t0 + UNR) < 1024;
        const float* pn = p + (size_t)(t0 + UNR) * 512;
        if (more) {
            #pragma unroll
            for (int j = 0; j < UNR; ++j) nxt[j] = pn[(size_t)j * 512];
        }
        #pragma unroll
        for (int j = 0; j < UNR; ++j) {
            h = fmaxf(fmaf(ur, h, cur[j]), 0.0f);
            p[(size_t)(t0 + j) * 512] = h;
        }
        #pragma unroll
        for (int j = 0; j < UNR; ++j) cur[j] = nxt[j];
    }
}

extern "C" void kernel_launch(void* const* d_in, const int* in_sizes, int n_in,
                              void* d_out, int out_size, void* d_ws, size_t ws_size,
                              hipStream_t stream) {
    const float* x = (const float*)d_in[0];   // [64,1024,512]
    const float* W = (const float*)d_in[1];   // [512,512]
    const float* u = (const float*)d_in[2];   // [512]
    const float* b = (const float*)d_in[3];   // [512]
    float* out = (float*)d_out;               // [64,1024,512] fp32

    const size_t WT_BYTES = (size_t)512 * 512 * 2;              // 512 KB bf16 Wt
    const size_t XP_BYTES = (size_t)64 * 1024 * 512 * 2;        // 64 MB fp16 xp (tiled)
    unsigned short* Wt = (unsigned short*)d_ws;
    __half* xp16 = (__half*)((char*)d_ws + WT_BYTES);
    const bool f16path = ws_size >= WT_BYTES + XP_BYTES;        // deterministic -> graph-safe

    dim3 tgrid(16, 16), tblk(32, 8);
    wt_kernel<<<tgrid, tblk, 0, stream>>>(W, Wt);

    dim3 grid(2048);                          // 1D; XCD-chunked remap inside kernel
    if (f16path) {
        gemm_bias_kernel<true><<<grid, 256, 0, stream>>>(x, Wt, b, nullptr, xp16);
        scan_t_kernel<<<512, 64, 0, stream>>>(xp16, out, u);
    } else {
        gemm_bias_kernel<false><<<grid, 256, 0, stream>>>(x, Wt, b, out, nullptr);
        scan_f32_kernel<<<512, 64, 0, stream>>>(out, u);
    }
}